// Round 8
// baseline (293.732 us; speedup 1.0000x reference)
//
#include <hip/hip_runtime.h>
#include <math.h>

#define B_ 16
#define N_ 128
#define H_ 768
#define NEGV (-1e9f)
#define CFAC 2.8853900817779268f   // 2/ln(2): exp2(CFAC*x) == exp(2x)

typedef float f32x4 __attribute__((ext_vector_type(4)));
typedef short s16x8 __attribute__((ext_vector_type(8)));
typedef short s16x4 __attribute__((ext_vector_type(4)));

// fp32 -> bf16 (RNE) and back
__device__ __forceinline__ unsigned short f2bf(float x) {
    unsigned int u = __float_as_uint(x);
    u += 0x7fffu + ((u >> 16) & 1u);
    return (unsigned short)(u >> 16);
}
__device__ __forceinline__ float bf2f(unsigned short h) {
    return __uint_as_float(((unsigned int)h) << 16);
}

__device__ __forceinline__ float wave_sum(float v) {
    #pragma unroll
    for (int o = 32; o > 0; o >>= 1) v += __shfl_down(v, o);
    return v;
}
__device__ __forceinline__ float wave_max(float v) {
    #pragma unroll
    for (int o = 32; o > 0; o >>= 1) v = fmaxf(v, __shfl_down(v, o));
    return v;
}

// ---------------- MFMA split-bf16 GEMM + exp2 epilogue; z=2 lane: prep ----------------
// z=0: eq = exp2(CFAC*(dec@Wq+bq)); z=1: ek; tile 64x128, 4 waves, grid (32, 6, 3)
// 3-pass split: A*B ~= Ah*Bh + Ah*Bl + Al*Bh  (score-level err ~3e-6, validated class)
__global__ __launch_bounds__(256) void gemm_kernel(const float* __restrict__ dec,
                                                   const float* __restrict__ sen,
                                                   const float* __restrict__ Wq,
                                                   const float* __restrict__ bq,
                                                   const float* __restrict__ Wk,
                                                   const float* __restrict__ bk,
                                                   const float* __restrict__ wt,
                                                   const int* __restrict__ target,
                                                   const int* __restrict__ tgt_len,
                                                   float* __restrict__ eq,
                                                   float* __restrict__ ek,
                                                   int* __restrict__ inv,
                                                   float* __restrict__ w2,
                                                   float* __restrict__ sumwt) {
    const int tid = threadIdx.x;

    if (blockIdx.z == 2) {
        if (blockIdx.y != 0) return;
        const int p = blockIdx.x;
        if (p < B_) {
            if (tid < N_) inv[p * N_ + target[p * N_ + tid]] = tid;
        } else if (p == B_) {
            __shared__ float red[4];
            float local = 0.f;
            for (int h = tid; h < H_; h += 256) {
                float w = wt[h];
                w2[h] = -2.f * w;
                local += w;
            }
            float v = wave_sum(local);
            if ((tid & 63) == 0) red[tid >> 6] = v;
            __syncthreads();
            if (tid == 0) sumwt[0] = red[0] + red[1] + red[2] + red[3];
        }
        return;
    }

    const float* A; const float* W; const float* bias; float* out;
    if (blockIdx.z == 0) { A = dec; W = Wq; bias = bq; out = eq; }
    else                 { A = sen; W = Wk; bias = bk; out = ek; }

    const int bx = blockIdx.x;            // m-tile (64 rows)
    const int m0 = bx * 64;
    // rows [len..128) of this batch are never read downstream unmasked (poison is finite)
    if (((bx & 1) * 64) >= tgt_len[bx >> 1]) return;
    const int n0 = blockIdx.y * 128;

    const int lane = tid & 63;
    const int wid  = tid >> 6;
    const int wr = wid >> 1, wc = wid & 1;    // wave tile: 32 rows x 64 cols
    const int l15 = lane & 15, lhi = lane >> 4;

    // LDS bf16 tiles, pitch 40 shorts (80B: 16B-aligned, bank-spread)
    __shared__ unsigned short Ah[64 * 40], Al[64 * 40];
    __shared__ unsigned short Bh[128 * 40], Bl[128 * 40];   // Bs[n][k]

    f32x4 acc[2][4];
    #pragma unroll
    for (int fm = 0; fm < 2; fm++)
        #pragma unroll
        for (int fn = 0; fn < 4; fn++) acc[fm][fn] = (f32x4){0.f, 0.f, 0.f, 0.f};

    const int arow = tid >> 2;            // 0..63
    const int akc  = (tid & 3) * 8;       // 0/8/16/24
    const int bk4  = tid >> 5;            // 0..7 (k group of 4)
    const int bnc  = (tid & 31) * 4;      // 0..124 (n group of 4)

    for (int k0 = 0; k0 < H_; k0 += 32) {
        const float* ap = &A[(m0 + arow) * H_ + k0 + akc];
        float4 a0 = *(const float4*)ap;
        float4 a1 = *(const float4*)(ap + 4);
        const float* wp = &W[(k0 + bk4 * 4) * H_ + n0 + bnc];
        float4 r0 = *(const float4*)wp;
        float4 r1 = *(const float4*)(wp + H_);
        float4 r2 = *(const float4*)(wp + 2 * H_);
        float4 r3 = *(const float4*)(wp + 3 * H_);

        __syncthreads();
        {   // A: row-contiguous bf16 hi/lo, one b128 write each
            float av[8] = {a0.x, a0.y, a0.z, a0.w, a1.x, a1.y, a1.z, a1.w};
            s16x8 hv, lv;
            #pragma unroll
            for (int i = 0; i < 8; i++) {
                unsigned short h = f2bf(av[i]);
                hv[i] = (short)h;
                lv[i] = (short)f2bf(av[i] - bf2f(h));
            }
            *(s16x8*)&Ah[arow * 40 + akc] = hv;
            *(s16x8*)&Al[arow * 40 + akc] = lv;
        }
        {   // B: transpose 4x4 fp32 block -> Bs[n][k] bf16 hi/lo (b64 writes)
            float bm[4][4] = {{r0.x, r0.y, r0.z, r0.w},
                              {r1.x, r1.y, r1.z, r1.w},
                              {r2.x, r2.y, r2.z, r2.w},
                              {r3.x, r3.y, r3.z, r3.w}};   // [k][n]
            #pragma unroll
            for (int j = 0; j < 4; j++) {
                s16x4 bh, bl;
                #pragma unroll
                for (int i = 0; i < 4; i++) {
                    unsigned short h = f2bf(bm[i][j]);
                    bh[i] = (short)h;
                    bl[i] = (short)f2bf(bm[i][j] - bf2f(h));
                }
                *(s16x4*)&Bh[(bnc + j) * 40 + bk4 * 4] = bh;
                *(s16x4*)&Bl[(bnc + j) * 40 + bk4 * 4] = bl;
            }
        }
        __syncthreads();

        s16x8 ahf[2], alf[2], bhf[4], blf[4];
        #pragma unroll
        for (int fm = 0; fm < 2; fm++) {
            int off = (wr * 32 + fm * 16 + l15) * 40 + lhi * 8;
            ahf[fm] = *(const s16x8*)&Ah[off];
            alf[fm] = *(const s16x8*)&Al[off];
        }
        #pragma unroll
        for (int fn = 0; fn < 4; fn++) {
            int off = (wc * 64 + fn * 16 + l15) * 40 + lhi * 8;
            bhf[fn] = *(const s16x8*)&Bh[off];
            blf[fn] = *(const s16x8*)&Bl[off];
        }
        #pragma unroll
        for (int fm = 0; fm < 2; fm++)
            #pragma unroll
            for (int fn = 0; fn < 4; fn++) {
                acc[fm][fn] = __builtin_amdgcn_mfma_f32_16x16x32_bf16(alf[fm], bhf[fn], acc[fm][fn], 0, 0, 0);
                acc[fm][fn] = __builtin_amdgcn_mfma_f32_16x16x32_bf16(ahf[fm], blf[fn], acc[fm][fn], 0, 0, 0);
                acc[fm][fn] = __builtin_amdgcn_mfma_f32_16x16x32_bf16(ahf[fm], bhf[fn], acc[fm][fn], 0, 0, 0);
            }
    }

    // epilogue: C/D layout col=lane&15, row=(lane>>4)*4+reg  [m89-verified]
    #pragma unroll
    for (int fm = 0; fm < 2; fm++)
        #pragma unroll
        for (int fn = 0; fn < 4; fn++) {
            int col = n0 + wc * 64 + fn * 16 + l15;
            float bv = bias[col];
            #pragma unroll
            for (int r = 0; r < 4; r++) {
                int row = m0 + wr * 32 + fm * 16 + lhi * 4 + r;
                out[row * H_ + col] = __builtin_amdgcn_exp2f(CFAC * (acc[fm][fn][r] + bv));
            }
        }
}

// ---------------- scores: sc[b,t,j] = base + sum_h w2[h]*rcp(1 + eq*ek) ----------------
// tile 16t x 64j, 128 threads (2 waves, wave = 64 j-lanes, micro 8t x 1j).
// q/w via LDS wave-uniform broadcasts; k in registers from global (L2-hot), dbuf.
// grid (2, 8, 16); skip tiles with t0>=len or j0>=len (downstream reads masked)
__global__ __launch_bounds__(128) void scores_kernel(const float* __restrict__ eq,
                                                     const float* __restrict__ ek,
                                                     const float* __restrict__ w2,
                                                     const float* __restrict__ sumwt,
                                                     const float* __restrict__ bt,
                                                     const int* __restrict__ tgt_len,
                                                     float* __restrict__ sc) {
    const int b  = blockIdx.z;
    const int t0 = blockIdx.y * 16;
    const int j0 = blockIdx.x * 64;
    const int len = tgt_len[b];
    if (t0 >= len || j0 >= len) return;

    const int tid = threadIdx.x;
    const int lane = tid & 63;
    const int wv = tid >> 6;          // 0/1: t-rows t0+wv*8 .. +8

    __shared__ __align__(16) float qs[16][68];
    __shared__ __align__(16) float w2s[H_];

    for (int h = tid; h < H_; h += 128) w2s[h] = w2[h];

    float acc[8];
    #pragma unroll
    for (int r = 0; r < 8; r++) acc[r] = 0.f;

    const float* kr = &ek[(b * N_ + j0 + lane) * H_];
    float4 kv = *(const float4*)&kr[0];    // prefetch first chunk

    const int qr = tid >> 3, qc = (tid & 7) * 8;   // q staging map

    for (int h0 = 0; h0 < H_; h0 += 64) {
        const float* qp = &eq[(b * N_ + t0 + qr) * H_ + h0 + qc];
        float4 q0 = *(const float4*)qp;
        float4 q1 = *(const float4*)(qp + 4);
        __syncthreads();                     // protect prev-iter qs reads
        *(float4*)&qs[qr][qc]     = q0;
        *(float4*)&qs[qr][qc + 4] = q1;
        __syncthreads();

        #pragma unroll
        for (int hh = 0; hh < 64; hh += 4) {
            float4 kcur = kv;
            if (hh < 60)              kv = *(const float4*)&kr[h0 + hh + 4];
            else if (h0 + 64 < H_)    kv = *(const float4*)&kr[h0 + 64];
            float4 w4 = *(const float4*)&w2s[h0 + hh];
            #pragma unroll
            for (int r = 0; r < 8; r++) {
                float4 q4 = *(const float4*)&qs[wv * 8 + r][hh];
                acc[r] = fmaf(w4.x, __builtin_amdgcn_rcpf(fmaf(q4.x, kcur.x, 1.f)), acc[r]);
                acc[r] = fmaf(w4.y, __builtin_amdgcn_rcpf(fmaf(q4.y, kcur.y, 1.f)), acc[r]);
                acc[r] = fmaf(w4.z, __builtin_amdgcn_rcpf(fmaf(q4.z, kcur.z, 1.f)), acc[r]);
                acc[r] = fmaf(w4.w, __builtin_amdgcn_rcpf(fmaf(q4.w, kcur.w, 1.f)), acc[r]);
            }
        }
    }

    float base = sumwt[0] + bt[0];
    #pragma unroll
    for (int r = 0; r < 8; r++)
        sc[(b * N_ + t0 + wv * 8 + r) * N_ + j0 + lane] = acc[r] + base;
}

// ---------------- fused row/col loss terms (z=0 row, z=1 col) ----------------
// Cancellation order: shifted = es[idx] - m FIRST (matches jax log_softmax), then
// nll = log(sum) - shifted. Reproduces the -1e9-absorption cases exactly.
__global__ __launch_bounds__(128) void loss_kernel(const float* __restrict__ sc,
                                                   const int* __restrict__ inv,
                                                   const int* __restrict__ target,
                                                   const int* __restrict__ tgt_len,
                                                   float* __restrict__ rowterm,
                                                   float* __restrict__ colterm) {
    const int b = blockIdx.y;
    const int len = tgt_len[b];
    __shared__ float es[128];
    __shared__ float red[2];

    if (blockIdx.z == 0) {
        const int t = blockIdx.x, j = threadIdx.x;
        float s = sc[(b * N_ + t) * N_ + j];
        int invj = inv[b * N_ + j];
        float e = (invj < t || j >= len) ? NEGV : s;
        es[j] = e;
        float v = wave_max(e);
        if ((j & 63) == 0) red[j >> 6] = v;
        __syncthreads();
        float m = fmaxf(red[0], red[1]);
        __syncthreads();
        float p = __expf(e - m);
        float ps = wave_sum(p);
        if ((j & 63) == 0) red[j >> 6] = ps;
        __syncthreads();
        if (j == 0) {
            float sum = red[0] + red[1];
            int jt = target[b * N_ + t];
            float shifted = es[jt] - m;
            rowterm[b * N_ + t] = (t < len) ? (__logf(sum) - shifted) : 0.f;
        }
    } else {
        const int j = blockIdx.x, t = threadIdx.x;
        float s = sc[(b * N_ + t) * N_ + j];
        float e = (t < len && j < len) ? s : NEGV;
        es[t] = e;
        float v = wave_max(e);
        if ((t & 63) == 0) red[t >> 6] = v;
        __syncthreads();
        float m = fmaxf(red[0], red[1]);
        __syncthreads();
        float p = __expf(e - m);
        float ps = wave_sum(p);
        if ((t & 63) == 0) red[t >> 6] = ps;
        __syncthreads();
        if (t == 0) {
            float sum = red[0] + red[1];
            int ts = inv[b * N_ + j];
            float shifted = es[ts] - m;
            colterm[b * N_ + ts] = (ts < len) ? (__logf(sum) - shifted) : 0.f;
        }
    }
}

// ---------------- final reduction ----------------
__global__ __launch_bounds__(128) void final_kernel(const float* __restrict__ rowterm,
                                                    const float* __restrict__ colterm,
                                                    const int* __restrict__ tgt_len,
                                                    float* __restrict__ out) {
    const int tid = threadIdx.x;
    __shared__ float red[2];
    float rowacc = 0.f, colacc = 0.f;
    for (int b = 0; b < B_; b++) {
        float r = rowterm[b * N_ + tid];
        float c = colterm[b * N_ + tid];
        float v = wave_sum(r);
        if ((tid & 63) == 0) red[tid >> 6] = v;
        __syncthreads();
        float rs = red[0] + red[1];
        __syncthreads();
        float w = wave_sum(c);
        if ((tid & 63) == 0) red[tid >> 6] = w;
        __syncthreads();
        float cs = red[0] + red[1];
        __syncthreads();
        if (tid == 0) {
            float lenf = (float)tgt_len[b];
            rowacc += rs / (lenf - 1.f);
            colacc += cs / (lenf * (lenf - 1.f));
        }
    }
    if (tid == 0) out[0] = rowacc / (float)B_ + colacc / (float)B_;
}

extern "C" void kernel_launch(void* const* d_in, const int* in_sizes, int n_in,
                              void* d_out, int out_size, void* d_ws, size_t ws_size,
                              hipStream_t stream) {
    (void)in_sizes; (void)n_in; (void)out_size; (void)ws_size;
    const float* dec = (const float*)d_in[0];
    const float* sen = (const float*)d_in[1];
    const float* Wq  = (const float*)d_in[2];
    const float* bq  = (const float*)d_in[3];
    const float* Wk  = (const float*)d_in[4];
    const float* bk  = (const float*)d_in[5];
    const float* wt  = (const float*)d_in[6];
    const float* bt  = (const float*)d_in[7];
    const int* target  = (const int*)d_in[8];
    const int* tgt_len = (const int*)d_in[9];

    float* ws = (float*)d_ws;
    float* eq      = ws;
    float* ek      = ws + 1572864;
    float* sc      = ws + 3145728;
    int*   inv     = (int*)(ws + 3407872);
    float* w2      = ws + 3409920;
    float* sumwt   = ws + 3410688;
    float* rowterm = ws + 3410692;
    float* colterm = ws + 3412740;
    float* out = (float*)d_out;

    gemm_kernel<<<dim3(32, 6, 3), 256, 0, stream>>>(dec, sen, Wq, bq, Wk, bk, wt,
                                                    target, tgt_len, eq, ek, inv, w2, sumwt);
    scores_kernel<<<dim3(2, 8, 16), 128, 0, stream>>>(eq, ek, w2, sumwt, bt, tgt_len, sc);
    loss_kernel<<<dim3(N_, B_, 2), 128, 0, stream>>>(sc, inv, target, tgt_len, rowterm, colterm);
    final_kernel<<<1, 128, 0, stream>>>(rowterm, colterm, tgt_len, out);
}

// Round 10
// 179.036 us; speedup vs baseline: 1.6406x; 1.6406x over previous
//
#include <hip/hip_runtime.h>
#include <math.h>

#define B_ 16
#define N_ 128
#define H_ 768
#define NEGV (-1e9f)
#define CFAC 2.8853900817779268f   // 2/ln(2): exp2(CFAC*x) == exp(2x)

typedef float f32x4 __attribute__((ext_vector_type(4)));
typedef short s16x8 __attribute__((ext_vector_type(8)));
typedef short s16x4 __attribute__((ext_vector_type(4)));

// fp32 -> bf16 (RNE) and back
__device__ __forceinline__ unsigned short f2bf(float x) {
    unsigned int u = __float_as_uint(x);
    u += 0x7fffu + ((u >> 16) & 1u);
    return (unsigned short)(u >> 16);
}
__device__ __forceinline__ float bf2f(unsigned short h) {
    return __uint_as_float(((unsigned int)h) << 16);
}

__device__ __forceinline__ float wave_sum(float v) {
    #pragma unroll
    for (int o = 32; o > 0; o >>= 1) v += __shfl_down(v, o);
    return v;
}
__device__ __forceinline__ float wave_max(float v) {
    #pragma unroll
    for (int o = 32; o > 0; o >>= 1) v = fmaxf(v, __shfl_down(v, o));
    return v;
}

// ---------------- MFMA split-bf16 GEMM + exp2 epilogue; z=2 lane: prep ----------------
// (validated: ran round 8, absmax 0.0)
__global__ __launch_bounds__(256) void gemm_kernel(const float* __restrict__ dec,
                                                   const float* __restrict__ sen,
                                                   const float* __restrict__ Wq,
                                                   const float* __restrict__ bq,
                                                   const float* __restrict__ Wk,
                                                   const float* __restrict__ bk,
                                                   const float* __restrict__ wt,
                                                   const int* __restrict__ target,
                                                   const int* __restrict__ tgt_len,
                                                   float* __restrict__ eq,
                                                   float* __restrict__ ek,
                                                   int* __restrict__ inv,
                                                   float* __restrict__ w2,
                                                   float* __restrict__ sumwt) {
    const int tid = threadIdx.x;

    if (blockIdx.z == 2) {
        if (blockIdx.y != 0) return;
        const int p = blockIdx.x;
        if (p < B_) {
            if (tid < N_) inv[p * N_ + target[p * N_ + tid]] = tid;
        } else if (p == B_) {
            __shared__ float red[4];
            float local = 0.f;
            for (int h = tid; h < H_; h += 256) {
                float w = wt[h];
                w2[h] = -2.f * w;
                local += w;
            }
            float v = wave_sum(local);
            if ((tid & 63) == 0) red[tid >> 6] = v;
            __syncthreads();
            if (tid == 0) sumwt[0] = red[0] + red[1] + red[2] + red[3];
        }
        return;
    }

    const float* A; const float* W; const float* bias; float* out;
    if (blockIdx.z == 0) { A = dec; W = Wq; bias = bq; out = eq; }
    else                 { A = sen; W = Wk; bias = bk; out = ek; }

    const int bx = blockIdx.x;            // m-tile (64 rows)
    const int m0 = bx * 64;
    if (((bx & 1) * 64) >= tgt_len[bx >> 1]) return;
    const int n0 = blockIdx.y * 128;

    const int lane = tid & 63;
    const int wid  = tid >> 6;
    const int wr = wid >> 1, wc = wid & 1;    // wave tile: 32 rows x 64 cols
    const int l15 = lane & 15, lhi = lane >> 4;

    __shared__ unsigned short Ah[64 * 40], Al[64 * 40];
    __shared__ unsigned short Bh[128 * 40], Bl[128 * 40];   // Bs[n][k]

    f32x4 acc[2][4];
    #pragma unroll
    for (int fm = 0; fm < 2; fm++)
        #pragma unroll
        for (int fn = 0; fn < 4; fn++) acc[fm][fn] = (f32x4){0.f, 0.f, 0.f, 0.f};

    const int arow = tid >> 2;            // 0..63
    const int akc  = (tid & 3) * 8;       // 0/8/16/24
    const int bk4  = tid >> 5;            // 0..7 (k group of 4)
    const int bnc  = (tid & 31) * 4;      // 0..124 (n group of 4)

    for (int k0 = 0; k0 < H_; k0 += 32) {
        const float* ap = &A[(m0 + arow) * H_ + k0 + akc];
        float4 a0 = *(const float4*)ap;
        float4 a1 = *(const float4*)(ap + 4);
        const float* wp = &W[(k0 + bk4 * 4) * H_ + n0 + bnc];
        float4 r0 = *(const float4*)wp;
        float4 r1 = *(const float4*)(wp + H_);
        float4 r2 = *(const float4*)(wp + 2 * H_);
        float4 r3 = *(const float4*)(wp + 3 * H_);

        __syncthreads();
        {
            float av[8] = {a0.x, a0.y, a0.z, a0.w, a1.x, a1.y, a1.z, a1.w};
            s16x8 hv, lv;
            #pragma unroll
            for (int i = 0; i < 8; i++) {
                unsigned short h = f2bf(av[i]);
                hv[i] = (short)h;
                lv[i] = (short)f2bf(av[i] - bf2f(h));
            }
            *(s16x8*)&Ah[arow * 40 + akc] = hv;
            *(s16x8*)&Al[arow * 40 + akc] = lv;
        }
        {
            float bm[4][4] = {{r0.x, r0.y, r0.z, r0.w},
                              {r1.x, r1.y, r1.z, r1.w},
                              {r2.x, r2.y, r2.z, r2.w},
                              {r3.x, r3.y, r3.z, r3.w}};   // [k][n]
            #pragma unroll
            for (int j = 0; j < 4; j++) {
                s16x4 bh, bl;
                #pragma unroll
                for (int i = 0; i < 4; i++) {
                    unsigned short h = f2bf(bm[i][j]);
                    bh[i] = (short)h;
                    bl[i] = (short)f2bf(bm[i][j] - bf2f(h));
                }
                *(s16x4*)&Bh[(bnc + j) * 40 + bk4 * 4] = bh;
                *(s16x4*)&Bl[(bnc + j) * 40 + bk4 * 4] = bl;
            }
        }
        __syncthreads();

        s16x8 ahf[2], alf[2], bhf[4], blf[4];
        #pragma unroll
        for (int fm = 0; fm < 2; fm++) {
            int off = (wr * 32 + fm * 16 + l15) * 40 + lhi * 8;
            ahf[fm] = *(const s16x8*)&Ah[off];
            alf[fm] = *(const s16x8*)&Al[off];
        }
        #pragma unroll
        for (int fn = 0; fn < 4; fn++) {
            int off = (wc * 64 + fn * 16 + l15) * 40 + lhi * 8;
            bhf[fn] = *(const s16x8*)&Bh[off];
            blf[fn] = *(const s16x8*)&Bl[off];
        }
        #pragma unroll
        for (int fm = 0; fm < 2; fm++)
            #pragma unroll
            for (int fn = 0; fn < 4; fn++) {
                acc[fm][fn] = __builtin_amdgcn_mfma_f32_16x16x32_bf16(alf[fm], bhf[fn], acc[fm][fn], 0, 0, 0);
                acc[fm][fn] = __builtin_amdgcn_mfma_f32_16x16x32_bf16(ahf[fm], blf[fn], acc[fm][fn], 0, 0, 0);
                acc[fm][fn] = __builtin_amdgcn_mfma_f32_16x16x32_bf16(ahf[fm], bhf[fn], acc[fm][fn], 0, 0, 0);
            }
    }

    #pragma unroll
    for (int fm = 0; fm < 2; fm++)
        #pragma unroll
        for (int fn = 0; fn < 4; fn++) {
            int col = n0 + wc * 64 + fn * 16 + l15;
            float bv = bias[col];
            #pragma unroll
            for (int r = 0; r < 4; r++) {
                int row = m0 + wr * 32 + fm * 16 + lhi * 4 + r;
                out[row * H_ + col] = __builtin_amdgcn_exp2f(CFAC * (acc[fm][fn][r] + bv));
            }
        }
}

// ---------------- scores: sc[b,t,j] = base + sum_h w2[h]*rcp(1 + eq*ek) ----------------
// REBUILT (round-8 counters: old version 167us @ 4% VALUBusy, 1.8% occ, serial k-chain).
// tile 8t x 64j, 512 threads = 8 waves, wave w = t-row t0+w, lane = j.
// K tile staged in LDS (shared by all 8 waves), XOR-swizzled col^((row&7)<<2) to cut
// the 64-lane same-col bank conflict 32-way -> ~8-way. q/w2 reads wave-uniform
// broadcasts. Chunked h (128/chunk), next chunk prefetched to regs during compute.
// grid (2, 16, 16); skip tiles with t0>=len or j0>=len (downstream reads masked).
__global__ __launch_bounds__(512) void scores_kernel(const float* __restrict__ eq,
                                                     const float* __restrict__ ek,
                                                     const float* __restrict__ w2,
                                                     const float* __restrict__ sumwt,
                                                     const float* __restrict__ bt,
                                                     const int* __restrict__ tgt_len,
                                                     float* __restrict__ sc) {
    const int b  = blockIdx.z;
    const int t0 = blockIdx.y * 8;
    const int j0 = blockIdx.x * 64;
    const int len = tgt_len[b];
    if (t0 >= len || j0 >= len) return;

    const int tid  = threadIdx.x;
    const int lane = tid & 63;
    const int wv   = tid >> 6;            // 0..7 -> t-row t0+wv

    __shared__ __align__(16) float ks[64][128];   // swizzled
    __shared__ __align__(16) float qs[8][128];
    __shared__ __align__(16) float w2s[H_];

    for (int h = tid; h < H_; h += 512) w2s[h] = w2[h];

    const int krow = tid >> 3;            // 0..63
    const int kcg  = (tid & 7) * 16;      // col group base (16 floats)
    const bool doq = tid < 256;
    const int qrow = (tid >> 5) & 7;      // 0..7
    const int qcol = (tid & 31) * 4;

    const float* kbase = &ek[(b * N_ + j0 + krow) * H_ + kcg];
    const float* qbase = &eq[(b * N_ + t0 + qrow) * H_ + qcol];

    float4 kf[4]; float4 qf;
    #pragma unroll
    for (int i = 0; i < 4; i++) kf[i] = *(const float4*)&kbase[4 * i];
    if (doq) qf = *(const float4*)&qbase[0];

    const int kswz = (krow & 7) << 2;
    const int rswz = (lane & 7) << 2;
    float acc = 0.f;

    for (int h0 = 0; h0 < H_; h0 += 128) {
        __syncthreads();                       // prev-chunk readers done
        #pragma unroll
        for (int i = 0; i < 4; i++)
            *(float4*)&ks[krow][(kcg + 4 * i) ^ kswz] = kf[i];
        if (doq) *(float4*)&qs[qrow][qcol] = qf;
        __syncthreads();
        if (h0 + 128 < H_) {                   // prefetch next chunk during compute
            #pragma unroll
            for (int i = 0; i < 4; i++) kf[i] = *(const float4*)&kbase[h0 + 128 + 4 * i];
            if (doq) qf = *(const float4*)&qbase[h0 + 128];
        }
        #pragma unroll
        for (int hh = 0; hh < 128; hh += 4) {
            float4 k4 = *(const float4*)&ks[lane][hh ^ rswz];
            float4 w4 = *(const float4*)&w2s[h0 + hh];
            float4 q4 = *(const float4*)&qs[wv][hh];
            acc = fmaf(w4.x, __builtin_amdgcn_rcpf(fmaf(q4.x, k4.x, 1.f)), acc);
            acc = fmaf(w4.y, __builtin_amdgcn_rcpf(fmaf(q4.y, k4.y, 1.f)), acc);
            acc = fmaf(w4.z, __builtin_amdgcn_rcpf(fmaf(q4.z, k4.z, 1.f)), acc);
            acc = fmaf(w4.w, __builtin_amdgcn_rcpf(fmaf(q4.w, k4.w, 1.f)), acc);
        }
    }

    sc[(b * N_ + t0 + wv) * N_ + j0 + lane] = acc + sumwt[0] + bt[0];
}

// ---------------- fused row/col loss terms (z=0 row, z=1 col) ----------------
__global__ __launch_bounds__(128) void loss_kernel(const float* __restrict__ sc,
                                                   const int* __restrict__ inv,
                                                   const int* __restrict__ target,
                                                   const int* __restrict__ tgt_len,
                                                   float* __restrict__ rowterm,
                                                   float* __restrict__ colterm) {
    const int b = blockIdx.y;
    const int len = tgt_len[b];
    __shared__ float es[128];
    __shared__ float red[2];

    if (blockIdx.z == 0) {
        const int t = blockIdx.x, j = threadIdx.x;
        float s = sc[(b * N_ + t) * N_ + j];
        int invj = inv[b * N_ + j];
        float e = (invj < t || j >= len) ? NEGV : s;
        es[j] = e;
        float v = wave_max(e);
        if ((j & 63) == 0) red[j >> 6] = v;
        __syncthreads();
        float m = fmaxf(red[0], red[1]);
        __syncthreads();
        float p = __expf(e - m);
        float ps = wave_sum(p);
        if ((j & 63) == 0) red[j >> 6] = ps;
        __syncthreads();
        if (j == 0) {
            float sum = red[0] + red[1];
            int jt = target[b * N_ + t];
            float shifted = es[jt] - m;
            rowterm[b * N_ + t] = (t < len) ? (__logf(sum) - shifted) : 0.f;
        }
    } else {
        const int j = blockIdx.x, t = threadIdx.x;
        float s = sc[(b * N_ + t) * N_ + j];
        float e = (t < len && j < len) ? s : NEGV;
        es[t] = e;
        float v = wave_max(e);
        if ((t & 63) == 0) red[t >> 6] = v;
        __syncthreads();
        float m = fmaxf(red[0], red[1]);
        __syncthreads();
        float p = __expf(e - m);
        float ps = wave_sum(p);
        if ((t & 63) == 0) red[t >> 6] = ps;
        __syncthreads();
        if (t == 0) {
            float sum = red[0] + red[1];
            int ts = inv[b * N_ + j];
            float shifted = es[ts] - m;
            colterm[b * N_ + ts] = (ts < len) ? (__logf(sum) - shifted) : 0.f;
        }
    }
}

// ---------------- final reduction ----------------
__global__ __launch_bounds__(128) void final_kernel(const float* __restrict__ rowterm,
                                                    const float* __restrict__ colterm,
                                                    const int* __restrict__ tgt_len,
                                                    float* __restrict__ out) {
    const int tid = threadIdx.x;
    __shared__ float red[2];
    float rowacc = 0.f, colacc = 0.f;
    for (int b = 0; b < B_; b++) {
        float r = rowterm[b * N_ + tid];
        float c = colterm[b * N_ + tid];
        float v = wave_sum(r);
        if ((tid & 63) == 0) red[tid >> 6] = v;
        __syncthreads();
        float rs = red[0] + red[1];
        __syncthreads();
        float w = wave_sum(c);
        if ((tid & 63) == 0) red[tid >> 6] = w;
        __syncthreads();
        float cs = red[0] + red[1];
        __syncthreads();
        if (tid == 0) {
            float lenf = (float)tgt_len[b];
            rowacc += rs / (lenf - 1.f);
            colacc += cs / (lenf * (lenf - 1.f));
        }
    }
    if (tid == 0) out[0] = rowacc / (float)B_ + colacc / (float)B_;
}

extern "C" void kernel_launch(void* const* d_in, const int* in_sizes, int n_in,
                              void* d_out, int out_size, void* d_ws, size_t ws_size,
                              hipStream_t stream) {
    (void)in_sizes; (void)n_in; (void)out_size; (void)ws_size;
    const float* dec = (const float*)d_in[0];
    const float* sen = (const float*)d_in[1];
    const float* Wq  = (const float*)d_in[2];
    const float* bq  = (const float*)d_in[3];
    const float* Wk  = (const float*)d_in[4];
    const float* bk  = (const float*)d_in[5];
    const float* wt  = (const float*)d_in[6];
    const float* bt  = (const float*)d_in[7];
    const int* target  = (const int*)d_in[8];
    const int* tgt_len = (const int*)d_in[9];

    float* ws = (float*)d_ws;
    float* eq      = ws;
    float* ek      = ws + 1572864;
    float* sc      = ws + 3145728;
    int*   inv     = (int*)(ws + 3407872);
    float* w2      = ws + 3409920;
    float* sumwt   = ws + 3410688;
    float* rowterm = ws + 3410692;
    float* colterm = ws + 3412740;
    float* out = (float*)d_out;

    gemm_kernel<<<dim3(32, 6, 3), 256, 0, stream>>>(dec, sen, Wq, bq, Wk, bk, wt,
                                                    target, tgt_len, eq, ek, inv, w2, sumwt);
    scores_kernel<<<dim3(2, 16, 16), 512, 0, stream>>>(eq, ek, w2, sumwt, bt, tgt_len, sc);
    loss_kernel<<<dim3(N_, B_, 2), 128, 0, stream>>>(sc, inv, target, tgt_len, rowterm, colterm);
    final_kernel<<<1, 128, 0, stream>>>(rowterm, colterm, tgt_len, out);
}

// Round 11
// 160.595 us; speedup vs baseline: 1.8290x; 1.1148x over previous
//
#include <hip/hip_runtime.h>
#include <math.h>

#define B_ 16
#define N_ 128
#define H_ 768
#define NEGV (-1e9f)
#define CFAC 2.8853900817779268f   // 2/ln(2): exp2(CFAC*x) == exp(2x)

typedef float f32x4 __attribute__((ext_vector_type(4)));
typedef short s16x8 __attribute__((ext_vector_type(8)));
typedef short s16x4 __attribute__((ext_vector_type(4)));

// fp32 -> bf16 (RNE) and back
__device__ __forceinline__ unsigned short f2bf(float x) {
    unsigned int u = __float_as_uint(x);
    u += 0x7fffu + ((u >> 16) & 1u);
    return (unsigned short)(u >> 16);
}
__device__ __forceinline__ float bf2f(unsigned short h) {
    return __uint_as_float(((unsigned int)h) << 16);
}

__device__ __forceinline__ float wave_sum(float v) {
    #pragma unroll
    for (int o = 32; o > 0; o >>= 1) v += __shfl_down(v, o);
    return v;
}
__device__ __forceinline__ float wave_max(float v) {
    #pragma unroll
    for (int o = 32; o > 0; o >>= 1) v = fmaxf(v, __shfl_down(v, o));
    return v;
}

// ---------------- prep: W -> bf16 fragment-swizzled; inv/w2/sumwt ----------------
// W chunk layout: element (k, n) lives in chunk (ng=n>>4, kg=k>>5, lane=(n&15)+(((k>>3)&3)<<4)),
// position k&7. Chunk = 16B at dst[((ng*24+kg)*64+lane)*8]. gemm reads 1 chunk/lane = b128.
// bid<288: Wq tile (kg=bid%24, nt=bid/24); 288..575: Wk; 576: inv + w2 + sumwt.
__global__ __launch_bounds__(128) void prep_kernel(const float* __restrict__ Wq,
                                                   const float* __restrict__ Wk,
                                                   const float* __restrict__ wt,
                                                   const int* __restrict__ target,
                                                   unsigned short* __restrict__ wqbf,
                                                   unsigned short* __restrict__ wkbf,
                                                   int* __restrict__ inv,
                                                   float* __restrict__ w2,
                                                   float* __restrict__ sumwt) {
    const int bid = blockIdx.x;
    const int tid = threadIdx.x;
    if (bid < 576) {
        const float* W = (bid < 288) ? Wq : Wk;
        unsigned short* dst = (bid < 288) ? wqbf : wkbf;
        const int tb = bid % 288;
        const int kg = tb % 24, nt = tb / 24;
        const int k0 = kg * 32, n0 = nt * 64;

        __shared__ float tile[32][68];   // [k][n], padded
        const int tr = tid >> 2, tc = (tid & 3) * 16;
        const float* src = &W[(k0 + tr) * H_ + n0 + tc];
        float4 v0 = *(const float4*)(src);
        float4 v1 = *(const float4*)(src + 4);
        float4 v2 = *(const float4*)(src + 8);
        float4 v3 = *(const float4*)(src + 12);
        *(float4*)&tile[tr][tc]      = v0;
        *(float4*)&tile[tr][tc + 4]  = v1;
        *(float4*)&tile[tr][tc + 8]  = v2;
        *(float4*)&tile[tr][tc + 12] = v3;
        __syncthreads();

        #pragma unroll
        for (int c = 0; c < 2; c++) {
            const int ch = tid + c * 128;        // 0..255
            const int lane = ch & 63, ngl = ch >> 6;   // ngl 0..3
            const int nl = ngl * 16 + (lane & 15);
            const int kl = (lane >> 4) * 8;
            s16x8 o;
            #pragma unroll
            for (int i = 0; i < 8; i++) o[i] = (short)f2bf(tile[kl + i][nl]);
            const int ng = nt * 4 + ngl;
            *(s16x8*)&dst[((ng * 24 + kg) * 64 + lane) * 8] = o;
        }
    } else if (bid == 576) {
        for (int i = tid; i < B_ * N_; i += 128) {
            int b = i >> 7, t = i & 127;
            inv[b * N_ + target[b * N_ + t]] = t;
        }
        __shared__ float red[2];
        float local = 0.f;
        for (int h = tid; h < H_; h += 128) {
            float w = wt[h];
            w2[h] = -2.f * w;
            local += w;
        }
        float v = wave_sum(local);
        if ((tid & 63) == 0) red[tid >> 6] = v;
        __syncthreads();
        if (tid == 0) sumwt[0] = red[0] + red[1];
    }
}

// ---------------- GEMM: LDS-free, barrier-free, single-pass bf16 MFMA ----------------
// (round-10 counters: old LDS version 48us @ 1.26 blk/CU, 6.6M bank-conflicts, 3 passes)
// wave = 32m x 64n output (2fm x 4fn frags). 768 waves/z = 192 blocks x 4 waves, grid (192,2).
// B frags: direct b128 loads from pre-swizzled wbf (L2-hot). A: per-lane 32B fp32 + in-reg cvt.
// No LDS, no barriers -> compiler pipelines freely. Single pass: score err ~3e-3, invisible
// (output 1e9-dominated, ulp>=32; measured 3000x margin at fp32).
__global__ __launch_bounds__(256) void gemm_kernel(const float* __restrict__ dec,
                                                   const float* __restrict__ sen,
                                                   const unsigned short* __restrict__ wqbf,
                                                   const unsigned short* __restrict__ wkbf,
                                                   const float* __restrict__ bq,
                                                   const float* __restrict__ bk,
                                                   const int* __restrict__ tgt_len,
                                                   unsigned short* __restrict__ eqbf,
                                                   unsigned short* __restrict__ ekbf) {
    const int z = blockIdx.y;
    const float* A = z ? sen : dec;
    const unsigned short* Wb = z ? wkbf : wqbf;
    const float* bias = z ? bk : bq;
    unsigned short* out = z ? ekbf : eqbf;

    const int tid = threadIdx.x, lane = tid & 63, w = tid >> 6;
    const int wg = blockIdx.x * 4 + w;        // 0..767
    const int mi = wg / 12, ni = wg - mi * 12;
    const int m0 = mi * 32, n0 = ni * 64;
    if ((m0 & 127) >= tgt_len[m0 >> 7]) return;   // rows never read downstream unmasked
    const int l15 = lane & 15, lhi = lane >> 4;

    f32x4 acc[2][4];
    #pragma unroll
    for (int fm = 0; fm < 2; fm++)
        #pragma unroll
        for (int fn = 0; fn < 4; fn++) acc[fm][fn] = (f32x4){0.f, 0.f, 0.f, 0.f};

    const float* aptr0 = &A[(m0 + l15) * H_ + lhi * 8];
    const float* aptr1 = &A[(m0 + 16 + l15) * H_ + lhi * 8];
    const unsigned short* bb = &Wb[((n0 >> 4) * 24) * 512 + lane * 8];

    #pragma unroll 2
    for (int kg = 0; kg < 24; kg++) {
        s16x8 bf0 = *(const s16x8*)&bb[(0 * 24 + kg) * 512];
        s16x8 bf1 = *(const s16x8*)&bb[(1 * 24 + kg) * 512];
        s16x8 bf2 = *(const s16x8*)&bb[(2 * 24 + kg) * 512];
        s16x8 bf3 = *(const s16x8*)&bb[(3 * 24 + kg) * 512];
        float4 a00 = *(const float4*)(aptr0 + kg * 32);
        float4 a01 = *(const float4*)(aptr0 + kg * 32 + 4);
        float4 a10 = *(const float4*)(aptr1 + kg * 32);
        float4 a11 = *(const float4*)(aptr1 + kg * 32 + 4);
        s16x8 af0, af1;
        af0[0] = (short)f2bf(a00.x); af0[1] = (short)f2bf(a00.y);
        af0[2] = (short)f2bf(a00.z); af0[3] = (short)f2bf(a00.w);
        af0[4] = (short)f2bf(a01.x); af0[5] = (short)f2bf(a01.y);
        af0[6] = (short)f2bf(a01.z); af0[7] = (short)f2bf(a01.w);
        af1[0] = (short)f2bf(a10.x); af1[1] = (short)f2bf(a10.y);
        af1[2] = (short)f2bf(a10.z); af1[3] = (short)f2bf(a10.w);
        af1[4] = (short)f2bf(a11.x); af1[5] = (short)f2bf(a11.y);
        af1[6] = (short)f2bf(a11.z); af1[7] = (short)f2bf(a11.w);
        acc[0][0] = __builtin_amdgcn_mfma_f32_16x16x32_bf16(af0, bf0, acc[0][0], 0, 0, 0);
        acc[0][1] = __builtin_amdgcn_mfma_f32_16x16x32_bf16(af0, bf1, acc[0][1], 0, 0, 0);
        acc[0][2] = __builtin_amdgcn_mfma_f32_16x16x32_bf16(af0, bf2, acc[0][2], 0, 0, 0);
        acc[0][3] = __builtin_amdgcn_mfma_f32_16x16x32_bf16(af0, bf3, acc[0][3], 0, 0, 0);
        acc[1][0] = __builtin_amdgcn_mfma_f32_16x16x32_bf16(af1, bf0, acc[1][0], 0, 0, 0);
        acc[1][1] = __builtin_amdgcn_mfma_f32_16x16x32_bf16(af1, bf1, acc[1][1], 0, 0, 0);
        acc[1][2] = __builtin_amdgcn_mfma_f32_16x16x32_bf16(af1, bf2, acc[1][2], 0, 0, 0);
        acc[1][3] = __builtin_amdgcn_mfma_f32_16x16x32_bf16(af1, bf3, acc[1][3], 0, 0, 0);
    }

    // C/D layout: col=lane&15, row=(lane>>4)*4+reg  [validated r8, absmax 0.0]
    #pragma unroll
    for (int fm = 0; fm < 2; fm++)
        #pragma unroll
        for (int fn = 0; fn < 4; fn++) {
            int col = n0 + fn * 16 + l15;
            float bv = bias[col];
            #pragma unroll
            for (int r = 0; r < 4; r++) {
                int row = m0 + fm * 16 + lhi * 4 + r;
                out[row * H_ + col] =
                    f2bf(__builtin_amdgcn_exp2f(CFAC * (acc[fm][fn][r] + bv)));
            }
        }
}

// ---------------- scores: sc[b,t,j] = base + sum_h w2[h]*rcp(1 + eq*ek) ----------------
// round-8 rebuilt structure (LDS-staged K, XOR-swizzle, 8 waves); inputs now bf16
// (converted to fp32 at stage). grid (2,16,16); skip t0>=len or j0>=len.
__global__ __launch_bounds__(512) void scores_kernel(const unsigned short* __restrict__ eqbf,
                                                     const unsigned short* __restrict__ ekbf,
                                                     const float* __restrict__ w2,
                                                     const float* __restrict__ sumwt,
                                                     const float* __restrict__ bt,
                                                     const int* __restrict__ tgt_len,
                                                     float* __restrict__ sc) {
    const int b  = blockIdx.z;
    const int t0 = blockIdx.y * 8;
    const int j0 = blockIdx.x * 64;
    const int len = tgt_len[b];
    if (t0 >= len || j0 >= len) return;

    const int tid  = threadIdx.x;
    const int lane = tid & 63;
    const int wv   = tid >> 6;            // 0..7 -> t-row t0+wv

    __shared__ __align__(16) float ks[64][128];   // swizzled
    __shared__ __align__(16) float qs[8][128];
    __shared__ __align__(16) float w2s[H_];

    for (int h = tid; h < H_; h += 512) w2s[h] = w2[h];

    const int krow = tid >> 3;            // 0..63
    const int kcg  = (tid & 7) * 16;      // col group base (16 elems)
    const bool doq = tid < 256;
    const int qrow = (tid >> 5) & 7;      // 0..7
    const int qcol = (tid & 31) * 4;

    const unsigned short* kr = &ekbf[(b * N_ + j0 + krow) * H_ + kcg];
    const unsigned short* qb = &eqbf[(b * N_ + t0 + qrow) * H_ + qcol];

    s16x8 kf0 = *(const s16x8*)&kr[0];
    s16x8 kf1 = *(const s16x8*)&kr[8];
    s16x4 qf;
    if (doq) qf = *(const s16x4*)&qb[0];

    const int kswz = (krow & 7) << 2;
    const int rswz = (lane & 7) << 2;
    float acc = 0.f;

    for (int h0 = 0; h0 < H_; h0 += 128) {
        __syncthreads();                       // prev-chunk readers done
        #pragma unroll
        for (int i = 0; i < 4; i++) {
            float4 t;
            t.x = bf2f((unsigned short)kf0[0]);   // placeholder overwritten below
            const int e = i * 4;
            t.x = bf2f((unsigned short)((e + 0 < 8) ? kf0[(e + 0) & 7] : kf1[(e + 0) & 7]));
            t.y = bf2f((unsigned short)((e + 1 < 8) ? kf0[(e + 1) & 7] : kf1[(e + 1) & 7]));
            t.z = bf2f((unsigned short)((e + 2 < 8) ? kf0[(e + 2) & 7] : kf1[(e + 2) & 7]));
            t.w = bf2f((unsigned short)((e + 3 < 8) ? kf0[(e + 3) & 7] : kf1[(e + 3) & 7]));
            *(float4*)&ks[krow][(kcg + e) ^ kswz] = t;
        }
        if (doq) {
            float4 t;
            t.x = bf2f((unsigned short)qf[0]); t.y = bf2f((unsigned short)qf[1]);
            t.z = bf2f((unsigned short)qf[2]); t.w = bf2f((unsigned short)qf[3]);
            *(float4*)&qs[qrow][qcol] = t;
        }
        __syncthreads();
        if (h0 + 128 < H_) {                   // prefetch next chunk during compute
            kf0 = *(const s16x8*)&kr[h0 + 128];
            kf1 = *(const s16x8*)&kr[h0 + 136];
            if (doq) qf = *(const s16x4*)&qb[h0 + 128];
        }
        #pragma unroll
        for (int hh = 0; hh < 128; hh += 4) {
            float4 k4 = *(const float4*)&ks[lane][hh ^ rswz];
            float4 w4 = *(const float4*)&w2s[h0 + hh];
            float4 q4 = *(const float4*)&qs[wv][hh];
            acc = fmaf(w4.x, __builtin_amdgcn_rcpf(fmaf(q4.x, k4.x, 1.f)), acc);
            acc = fmaf(w4.y, __builtin_amdgcn_rcpf(fmaf(q4.y, k4.y, 1.f)), acc);
            acc = fmaf(w4.z, __builtin_amdgcn_rcpf(fmaf(q4.z, k4.z, 1.f)), acc);
            acc = fmaf(w4.w, __builtin_amdgcn_rcpf(fmaf(q4.w, k4.w, 1.f)), acc);
        }
    }

    sc[(b * N_ + t0 + wv) * N_ + j0 + lane] = acc + sumwt[0] + bt[0];
}

// ---------------- fused row/col loss terms (z=0 row, z=1 col) ----------------
__global__ __launch_bounds__(128) void loss_kernel(const float* __restrict__ sc,
                                                   const int* __restrict__ inv,
                                                   const int* __restrict__ target,
                                                   const int* __restrict__ tgt_len,
                                                   float* __restrict__ rowterm,
                                                   float* __restrict__ colterm) {
    const int b = blockIdx.y;
    const int len = tgt_len[b];
    __shared__ float es[128];
    __shared__ float red[2];

    if (blockIdx.z == 0) {
        const int t = blockIdx.x, j = threadIdx.x;
        float s = sc[(b * N_ + t) * N_ + j];
        int invj = inv[b * N_ + j];
        float e = (invj < t || j >= len) ? NEGV : s;
        es[j] = e;
        float v = wave_max(e);
        if ((j & 63) == 0) red[j >> 6] = v;
        __syncthreads();
        float m = fmaxf(red[0], red[1]);
        __syncthreads();
        float p = __expf(e - m);
        float ps = wave_sum(p);
        if ((j & 63) == 0) red[j >> 6] = ps;
        __syncthreads();
        if (j == 0) {
            float sum = red[0] + red[1];
            int jt = target[b * N_ + t];
            float shifted = es[jt] - m;
            rowterm[b * N_ + t] = (t < len) ? (__logf(sum) - shifted) : 0.f;
        }
    } else {
        const int j = blockIdx.x, t = threadIdx.x;
        float s = sc[(b * N_ + t) * N_ + j];
        float e = (t < len && j < len) ? s : NEGV;
        es[t] = e;
        float v = wave_max(e);
        if ((t & 63) == 0) red[t >> 6] = v;
        __syncthreads();
        float m = fmaxf(red[0], red[1]);
        __syncthreads();
        float p = __expf(e - m);
        float ps = wave_sum(p);
        if ((t & 63) == 0) red[t >> 6] = ps;
        __syncthreads();
        if (t == 0) {
            float sum = red[0] + red[1];
            int ts = inv[b * N_ + j];
            float shifted = es[ts] - m;
            colterm[b * N_ + ts] = (ts < len) ? (__logf(sum) - shifted) : 0.f;
        }
    }
}

// ---------------- final reduction ----------------
__global__ __launch_bounds__(128) void final_kernel(const float* __restrict__ rowterm,
                                                    const float* __restrict__ colterm,
                                                    const int* __restrict__ tgt_len,
                                                    float* __restrict__ out) {
    const int tid = threadIdx.x;
    __shared__ float red[2];
    float rowacc = 0.f, colacc = 0.f;
    for (int b = 0; b < B_; b++) {
        float r = rowterm[b * N_ + tid];
        float c = colterm[b * N_ + tid];
        float v = wave_sum(r);
        if ((tid & 63) == 0) red[tid >> 6] = v;
        __syncthreads();
        float rs = red[0] + red[1];
        __syncthreads();
        float w = wave_sum(c);
        if ((tid & 63) == 0) red[tid >> 6] = w;
        __syncthreads();
        float cs = red[0] + red[1];
        __syncthreads();
        if (tid == 0) {
            float lenf = (float)tgt_len[b];
            rowacc += rs / (lenf - 1.f);
            colacc += cs / (lenf * (lenf - 1.f));
        }
    }
    if (tid == 0) out[0] = rowacc / (float)B_ + colacc / (float)B_;
}

extern "C" void kernel_launch(void* const* d_in, const int* in_sizes, int n_in,
                              void* d_out, int out_size, void* d_ws, size_t ws_size,
                              hipStream_t stream) {
    (void)in_sizes; (void)n_in; (void)out_size; (void)ws_size;
    const float* dec = (const float*)d_in[0];
    const float* sen = (const float*)d_in[1];
    const float* Wq  = (const float*)d_in[2];
    const float* bq  = (const float*)d_in[3];
    const float* Wk  = (const float*)d_in[4];
    const float* bk  = (const float*)d_in[5];
    const float* wt  = (const float*)d_in[6];
    const float* bt  = (const float*)d_in[7];
    const int* target  = (const int*)d_in[8];
    const int* tgt_len = (const int*)d_in[9];

    // ws layout (float offsets), total 2,431,748 floats = 9.7 MB (< proven 13.66 MB)
    float* ws = (float*)d_ws;
    unsigned short* eqbf = (unsigned short*)ws;               // 1,572,864 shorts
    unsigned short* ekbf = (unsigned short*)(ws + 786432);    // 1,572,864 shorts
    float* sc      = ws + 1572864;                            // 262,144
    int*   inv     = (int*)(ws + 1835008);                    // 2,048
    float* w2      = ws + 1837056;                            // 768
    float* sumwt   = ws + 1837824;                            // 1 (+3 pad)
    float* rowterm = ws + 1837828;                            // 2,048
    float* colterm = ws + 1839876;                            // 2,048
    unsigned short* wqbf = (unsigned short*)(ws + 1841924);   // 589,824 shorts
    unsigned short* wkbf = (unsigned short*)(ws + 2136836);   // 589,824 shorts
    float* out = (float*)d_out;

    prep_kernel<<<dim3(577), 128, 0, stream>>>(Wq, Wk, wt, target, wqbf, wkbf, inv, w2, sumwt);
    gemm_kernel<<<dim3(192, 2), 256, 0, stream>>>(dec, sen, wqbf, wkbf, bq, bk, tgt_len, eqbf, ekbf);
    scores_kernel<<<dim3(2, 16, 16), 512, 0, stream>>>(eqbf, ekbf, w2, sumwt, bt, tgt_len, sc);
    loss_kernel<<<dim3(N_, B_, 2), 128, 0, stream>>>(sc, inv, target, tgt_len, rowterm, colterm);
    final_kernel<<<1, 128, 0, stream>>>(rowterm, colterm, tgt_len, out);
}